// Round 1
// baseline (1416.755 us; speedup 1.0000x reference)
//
#include <hip/hip_runtime.h>
#include <hip/hip_bf16.h>

// Problem constants
#define BATCH 4096
#define NGENE 3000
#define HID   6
#define GPT   30      // genes per term
#define T0N   500
#define T1N   50
#define NTERM 551     // T0+T1+1
#define NCOL  16530   // NTERM*GPT
#define KP    3008    // K padded to mult of 32
#define NP    16640   // N padded to mult of 128
#define OUTW  3857    // 551 aux + 3306 nn
#define BNEPS 1e-5f

typedef __attribute__((ext_vector_type(8))) __bf16 bf16x8;
typedef __attribute__((ext_vector_type(4))) float f32x4;

__device__ __forceinline__ unsigned short f2bf(float f) {
  unsigned int u = __builtin_bit_cast(unsigned int, f);
  u = (u + 0x7fffu + ((u >> 16) & 1u)) >> 16;
  return (unsigned short)u;
}

__device__ __forceinline__ void gload_lds16(const void* g, void* l) {
  __builtin_amdgcn_global_load_lds(
      (const __attribute__((address_space(1))) unsigned int*)g,
      (__attribute__((address_space(3))) unsigned int*)l, 16, 0, 0);
}

// ---- cast kernels: fp32 -> bf16 with zero padding ----
__global__ void cast_cell(const float* __restrict__ x, unsigned short* __restrict__ y) {
  int idx = blockIdx.x * 256 + threadIdx.x;    // < 4096*3008
  int r = idx / KP, c = idx - r * KP;
  float v = (c < NGENE) ? x[r * NGENE + c] : 0.f;
  y[idx] = f2bf(v);
}

__global__ void cast_wdg(const float* __restrict__ w, unsigned short* __restrict__ y) {
  int idx = blockIdx.x * 256 + threadIdx.x;    // < 16640*3008
  int r = idx / KP, c = idx - r * KP;
  float v = (r < NCOL && c < NGENE) ? w[r * NGENE + c] : 0.f;
  y[idx] = f2bf(v);
}

// ---- GEMM: C[m,n] = sum_k A[m,k]*Bt[n,k] + bdg[n]  (m97 structure) ----
__global__ __launch_bounds__(256) void gemm_dg(
    const unsigned short* __restrict__ A,    // [4096][KP] bf16
    const unsigned short* __restrict__ Bt,   // [NP][KP] bf16
    const float* __restrict__ bdg,           // [NCOL]
    float* __restrict__ C) {                 // [4096][NP] fp32
  __shared__ unsigned short smem[8192];      // As: [0,4096), Bs: [4096,8192)
  const int tid  = threadIdx.x;
  const int wave = tid >> 6, lane = tid & 63;
  const int wm = wave >> 1, wn = wave & 1;
  const int quad = lane >> 4, fr = lane & 15;
  const int m0 = blockIdx.y * 128, n0 = blockIdx.x * 128;
  const int lrow = lane >> 2;          // 0..15 within chunk
  const int lcol = (lane & 3) * 8;     // k element offset

  f32x4 acc[16] = {};

  for (int kt = 0; kt < KP / 32; ++kt) {
    const int k0 = kt * 32;
    // stage 16 KB (A tile 8KB + B tile 8KB) as 16 chunks of 1KB, 4 per wave
#pragma unroll
    for (int q = 0; q < 4; ++q) {
      int chunk = q * 4 + wave;                       // wave-uniform
      const unsigned short* gsrc;
      if (chunk < 8) {
        int row = m0 + chunk * 16 + lrow;
        gsrc = A + (size_t)row * KP + k0 + lcol;
      } else {
        int row = n0 + (chunk - 8) * 16 + lrow;
        gsrc = Bt + (size_t)row * KP + k0 + lcol;
      }
      gload_lds16(gsrc, &smem[chunk * 512]);
    }
    asm volatile("s_waitcnt vmcnt(0)" ::: "memory");
    __syncthreads();

    bf16x8 af[4], bfr[4];
#pragma unroll
    for (int tm = 0; tm < 4; ++tm)
      af[tm] = ((const bf16x8*)smem)[((wm * 64 + tm * 16 + fr) * 32 + quad * 8) >> 3];
#pragma unroll
    for (int tn = 0; tn < 4; ++tn)
      bfr[tn] = ((const bf16x8*)smem)[(4096 + (wn * 64 + tn * 16 + fr) * 32 + quad * 8) >> 3];
#pragma unroll
    for (int tm = 0; tm < 4; ++tm)
#pragma unroll
      for (int tn = 0; tn < 4; ++tn)
        acc[tm * 4 + tn] = __builtin_amdgcn_mfma_f32_16x16x32_bf16(
            af[tm], bfr[tn], acc[tm * 4 + tn], 0, 0, 0);
    __syncthreads();
  }

  // epilogue: + bdg, store fp32
#pragma unroll
  for (int tm = 0; tm < 4; ++tm) {
#pragma unroll
    for (int tn = 0; tn < 4; ++tn) {
      int n = n0 + wn * 64 + tn * 16 + fr;
      float bias = (n < NCOL) ? bdg[n] : 0.f;
#pragma unroll
      for (int r = 0; r < 4; ++r) {
        int m = m0 + wm * 64 + tm * 16 + quad * 4 + r;
        C[(size_t)m * NP + n] = acc[tm * 4 + tn][r] + bias;
      }
    }
  }
}

// ---- layer 0: z0 = tanh(dg[:, :500] @ W0^T + b0), written into out n0 slots ----
__global__ void layer0_z(const float* __restrict__ dg, const float* __restrict__ W0,
                         const float* __restrict__ b0, float* __restrict__ out) {
  int t = blockIdx.x * 256 + threadIdx.x;
  int b = blockIdx.y;
  if (t >= T0N) return;
  const float* d = dg + (size_t)b * NP + t * GPT;
  float x[GPT];
#pragma unroll
  for (int g = 0; g < GPT; ++g) x[g] = d[g];
  float* o = out + (size_t)b * OUTW + 551 + t * HID;
#pragma unroll
  for (int h = 0; h < HID; ++h) {
    const float* w = W0 + (t * HID + h) * GPT;
    float s = b0[t * HID + h];
#pragma unroll
    for (int g = 0; g < GPT; ++g) s += x[g] * w[g];
    o[h] = tanhf(s);
  }
}

// ---- column stats (sum, sumsq) over batch via 32 row-group partial atomics ----
__global__ void colstats(const float* __restrict__ out, int off, int ncols,
                         float* __restrict__ st) {
  int c = blockIdx.x * 256 + threadIdx.x;
  if (c >= ncols) return;
  int r0 = blockIdx.y * 128;
  float s = 0.f, q = 0.f;
  for (int r = 0; r < 128; ++r) {
    float v = out[(size_t)(r0 + r) * OUTW + off + c];
    s += v; q += v * v;
  }
  atomicAdd(&st[2 * c], s);
  atomicAdd(&st[2 * c + 1], q);
}

// ---- BN finalize: scale = gam/sqrt(var+eps), shift = bet - mean*scale ----
__global__ void bnfin(const float* __restrict__ st, const float* __restrict__ gam,
                      const float* __restrict__ bet, float* __restrict__ ss, int ncols) {
  int c = blockIdx.x * 256 + threadIdx.x;
  if (c >= ncols) return;
  float m = st[2 * c] * (1.f / BATCH);
  float v = st[2 * c + 1] * (1.f / BATCH) - m * m;
  float sc = gam[c] * rsqrtf(v + BNEPS);
  ss[2 * c] = sc;
  ss[2 * c + 1] = bet[c] - m * sc;
}

// ---- normalize n0 in place + aux0 ----
__global__ void norm0_aux0(float* out, const float* __restrict__ ss,
                           const float* __restrict__ aw, const float* __restrict__ ab,
                           const float* __restrict__ av, const float* __restrict__ ac) {
  int t = blockIdx.x * 256 + threadIdx.x;
  int b = blockIdx.y;
  if (t >= T0N) return;
  float* o = out + (size_t)b * OUTW;
  float s = ab[t];
#pragma unroll
  for (int h = 0; h < HID; ++h) {
    int c = t * HID + h;
    float n = o[551 + c] * ss[2 * c] + ss[2 * c + 1];
    o[551 + c] = n;
    s += n * aw[c];
  }
  o[t] = tanhf(s) * av[t] + ac[t];
}

// ---- layer 1: z1 = tanh(concat(n0 children, dg mid) @ W1^T + b1) ----
__global__ void layer1_z(const float* __restrict__ dg, const float* __restrict__ W1,
                         const float* __restrict__ b1, float* out) {
  int idx = blockIdx.x * 256 + threadIdx.x;
  if (idx >= BATCH * T1N) return;
  int b = idx / T1N, t = idx - b * T1N;
  const float* n0 = out + (size_t)b * OUTW + 551 + t * 60;
  const float* d  = dg + (size_t)b * NP + (T0N + t) * GPT;
  float x[90];
#pragma unroll
  for (int i = 0; i < 60; ++i) x[i] = n0[i];
#pragma unroll
  for (int g = 0; g < GPT; ++g) x[60 + g] = d[g];
  float* o = out + (size_t)b * OUTW + 3551 + t * HID;
#pragma unroll
  for (int h = 0; h < HID; ++h) {
    const float* w = W1 + (t * HID + h) * 90;
    float s = b1[t * HID + h];
#pragma unroll
    for (int i = 0; i < 90; ++i) s += x[i] * w[i];
    o[h] = tanhf(s);
  }
}

// ---- normalize n1 in place + aux1 ----
__global__ void norm1_aux1(float* out, const float* __restrict__ ss,
                           const float* __restrict__ aw, const float* __restrict__ ab,
                           const float* __restrict__ av, const float* __restrict__ ac) {
  int idx = blockIdx.x * 256 + threadIdx.x;
  if (idx >= BATCH * T1N) return;
  int b = idx / T1N, t = idx - b * T1N;
  float* o = out + (size_t)b * OUTW;
  float s = ab[t];
#pragma unroll
  for (int h = 0; h < HID; ++h) {
    int c = t * HID + h;
    float n = o[3551 + c] * ss[2 * c] + ss[2 * c + 1];
    o[3551 + c] = n;
    s += n * aw[c];
  }
  o[500 + t] = tanhf(s) * av[t] + ac[t];
}

// ---- root: z2 = tanh(concat(n1, dg root) @ W2^T + b2) ----
__global__ void root_z(const float* __restrict__ dg, const float* __restrict__ W2,
                       const float* __restrict__ b2, float* out) {
  int b = blockIdx.x * 256 + threadIdx.x;
  if (b >= BATCH) return;
  const float* n1 = out + (size_t)b * OUTW + 3551;
  const float* d  = dg + (size_t)b * NP + 550 * GPT;
  float* o = out + (size_t)b * OUTW + 3851;
#pragma unroll
  for (int h = 0; h < HID; ++h) {
    const float* w = W2 + h * 330;
    float s = b2[h];
    for (int i = 0; i < 300; ++i) s += n1[i] * w[i];
#pragma unroll
    for (int g = 0; g < GPT; ++g) s += d[g] * w[300 + g];
    o[h] = tanhf(s);
  }
}

// ---- normalize n2 in place + aux2 ----
__global__ void norm2_aux2(float* out, const float* __restrict__ ss,
                           const float* __restrict__ aw, const float* __restrict__ ab,
                           const float* __restrict__ av, const float* __restrict__ ac) {
  int b = blockIdx.x * 256 + threadIdx.x;
  if (b >= BATCH) return;
  float* o = out + (size_t)b * OUTW;
  float s = ab[0];
#pragma unroll
  for (int h = 0; h < HID; ++h) {
    float n = o[3851 + h] * ss[2 * h] + ss[2 * h + 1];
    o[3851 + h] = n;
    s += n * aw[h];
  }
  o[550] = tanhf(s) * av[0] + ac[0];
}

extern "C" void kernel_launch(void* const* d_in, const int* in_sizes, int n_in,
                              void* d_out, int out_size, void* d_ws, size_t ws_size,
                              hipStream_t stream) {
  (void)in_sizes; (void)n_in; (void)out_size; (void)ws_size;
  const float* cell = (const float*)d_in[0];
  const float* Wdg  = (const float*)d_in[1];
  const float* bdg  = (const float*)d_in[2];
  const float* W0   = (const float*)d_in[3];
  const float* b0   = (const float*)d_in[4];
  const float* gam0 = (const float*)d_in[5];
  const float* bet0 = (const float*)d_in[6];
  const float* aw0  = (const float*)d_in[7];
  const float* ab0  = (const float*)d_in[8];
  const float* av0  = (const float*)d_in[9];
  const float* ac0  = (const float*)d_in[10];
  const float* W1   = (const float*)d_in[11];
  const float* b1   = (const float*)d_in[12];
  const float* gam1 = (const float*)d_in[13];
  const float* bet1 = (const float*)d_in[14];
  const float* aw1  = (const float*)d_in[15];
  const float* ab1  = (const float*)d_in[16];
  const float* av1  = (const float*)d_in[17];
  const float* ac1  = (const float*)d_in[18];
  const float* W2   = (const float*)d_in[19];
  const float* b2   = (const float*)d_in[20];
  const float* gam2 = (const float*)d_in[21];
  const float* bet2 = (const float*)d_in[22];
  const float* aw2  = (const float*)d_in[23];
  const float* ab2  = (const float*)d_in[24];
  const float* av2  = (const float*)d_in[25];
  const float* ac2  = (const float*)d_in[26];
  float* out = (float*)d_out;

  char* ws = (char*)d_ws;
  unsigned short* cellb = (unsigned short*)(ws);                 // 4096*3008*2  = 24,641,536
  unsigned short* wdgb  = (unsigned short*)(ws + 24641536);      // 16640*3008*2 = 100,106,240
  float*          dg    = (float*)(ws + 124747776);              // 4096*16640*4 = 272,629,760
  float*          st    = (float*)(ws + 397377536);              // 3306*2 floats
  float*          ssb   = (float*)(ws + 397403984);              // 3306*2 floats

  hipMemsetAsync(st, 0, 3306 * 2 * sizeof(float), stream);
  cast_cell<<<48128, 256, 0, stream>>>(cell, cellb);
  cast_wdg<<<195520, 256, 0, stream>>>(Wdg, wdgb);
  gemm_dg<<<dim3(130, 32), 256, 0, stream>>>(cellb, wdgb, bdg, dg);

  layer0_z<<<dim3(2, BATCH), 256, 0, stream>>>(dg, W0, b0, out);
  colstats<<<dim3(12, 32), 256, 0, stream>>>(out, 551, 3000, st);
  bnfin<<<12, 256, 0, stream>>>(st, gam0, bet0, ssb, 3000);
  norm0_aux0<<<dim3(2, BATCH), 256, 0, stream>>>(out, ssb, aw0, ab0, av0, ac0);

  layer1_z<<<800, 256, 0, stream>>>(dg, W1, b1, out);
  colstats<<<dim3(2, 32), 256, 0, stream>>>(out, 3551, 300, st + 2 * 3000);
  bnfin<<<2, 256, 0, stream>>>(st + 2 * 3000, gam1, bet1, ssb + 2 * 3000, 300);
  norm1_aux1<<<800, 256, 0, stream>>>(out, ssb + 2 * 3000, aw1, ab1, av1, ac1);

  root_z<<<16, 256, 0, stream>>>(dg, W2, b2, out);
  colstats<<<dim3(1, 32), 256, 0, stream>>>(out, 3851, 6, st + 2 * 3300);
  bnfin<<<1, 256, 0, stream>>>(st + 2 * 3300, gam2, bet2, ssb + 2 * 3300, 6);
  norm2_aux2<<<16, 256, 0, stream>>>(out, ssb + 2 * 3300, aw2, ab2, av2, ac2);
}

// Round 2
// 1190.030 us; speedup vs baseline: 1.1905x; 1.1905x over previous
//
#include <hip/hip_runtime.h>
#include <hip/hip_bf16.h>

#define BATCH 4096
#define NGENE 3000
#define HID   6
#define GPT   30
#define T0N   500
#define T1N   50
#define NCOL  16530   // 551*30
#define KP    3008    // K padded
#define NP    16640   // dg rows padded to 128
#define OUTW  3857
#define BNEPS 1e-5f

typedef __attribute__((ext_vector_type(8))) __bf16 bf16x8;
typedef __attribute__((ext_vector_type(4))) float f32x4;
typedef __attribute__((ext_vector_type(8))) unsigned short ushort8;

__device__ __forceinline__ unsigned short f2bf(float f) {
  unsigned int u = __builtin_bit_cast(unsigned int, f);
  u = (u + 0x7fffu + ((u >> 16) & 1u)) >> 16;
  return (unsigned short)u;
}

__device__ __forceinline__ void gload_lds16(const void* g, void* l) {
  __builtin_amdgcn_global_load_lds(
      (const __attribute__((address_space(1))) unsigned int*)g,
      (__attribute__((address_space(3))) unsigned int*)l, 16, 0, 0);
}

// ---- vectorized casts: 8 floats -> 8 bf16 per thread, zero padding ----
// rows*KP/8 threads; chunks of 8 along k. NGENE=3000=375*8 exactly, so chunk
// 375 (cols 3000..3007) is pure padding.
__global__ void cast_cell(const float* __restrict__ x, ushort8* __restrict__ y) {
  int idx = blockIdx.x * 256 + threadIdx.x;     // < 4096*376
  int r = idx / 376, c8 = idx - r * 376;
  int c = c8 * 8;
  ushort8 o = (ushort8)0;
  if (c < NGENE) {
    const float4* p = (const float4*)(x + (size_t)r * NGENE + c);
    float4 a = p[0], b = p[1];
    o[0] = f2bf(a.x); o[1] = f2bf(a.y); o[2] = f2bf(a.z); o[3] = f2bf(a.w);
    o[4] = f2bf(b.x); o[5] = f2bf(b.y); o[6] = f2bf(b.z); o[7] = f2bf(b.w);
  }
  y[idx] = o;
}

__global__ void cast_wdg(const float* __restrict__ w, ushort8* __restrict__ y) {
  int idx = blockIdx.x * 256 + threadIdx.x;     // < 16640*376
  int r = idx / 376, c8 = idx - r * 376;
  int c = c8 * 8;
  ushort8 o = (ushort8)0;
  if (r < NCOL && c < NGENE) {
    const float4* p = (const float4*)(w + (size_t)r * NGENE + c);
    float4 a = p[0], b = p[1];
    o[0] = f2bf(a.x); o[1] = f2bf(a.y); o[2] = f2bf(a.z); o[3] = f2bf(a.w);
    o[4] = f2bf(b.x); o[5] = f2bf(b.y); o[6] = f2bf(b.z); o[7] = f2bf(b.w);
  }
  y[idx] = o;
}

// ---- GEMM (transposed output): dgT[m][b] = Wdg[m,:]·cell[b,:] + bdg[m] ----
// A = wdgb [NP][KP], Bt = cellb [BATCH][KP], C = dgT [NP][BATCH].
// Grid (x = batch tiles = 32 innermost for L2 reuse of A-tile, y = 130).
__global__ __launch_bounds__(256) void gemm_dgT(
    const unsigned short* __restrict__ A,
    const unsigned short* __restrict__ Bt,
    const float* __restrict__ bdg,
    float* __restrict__ C) {
  __shared__ unsigned short smem[8192];
  const int tid  = threadIdx.x;
  const int wave = tid >> 6, lane = tid & 63;
  const int wm = wave >> 1, wn = wave & 1;
  const int quad = lane >> 4, fr = lane & 15;
  const int m0 = blockIdx.y * 128, n0 = blockIdx.x * 128;
  const int lrow = lane >> 2;
  const int lcol = (lane & 3) * 8;

  f32x4 acc[16] = {};

  for (int kt = 0; kt < KP / 32; ++kt) {
    const int k0 = kt * 32;
#pragma unroll
    for (int q = 0; q < 4; ++q) {
      int chunk = q * 4 + wave;
      const unsigned short* gsrc;
      if (chunk < 8) {
        int row = m0 + chunk * 16 + lrow;
        gsrc = A + (size_t)row * KP + k0 + lcol;
      } else {
        int row = n0 + (chunk - 8) * 16 + lrow;
        gsrc = Bt + (size_t)row * KP + k0 + lcol;
      }
      gload_lds16(gsrc, &smem[chunk * 512]);
    }
    asm volatile("s_waitcnt vmcnt(0)" ::: "memory");
    __syncthreads();

    bf16x8 af[4], bfr[4];
#pragma unroll
    for (int tm = 0; tm < 4; ++tm)
      af[tm] = ((const bf16x8*)smem)[((wm * 64 + tm * 16 + fr) * 32 + quad * 8) >> 3];
#pragma unroll
    for (int tn = 0; tn < 4; ++tn)
      bfr[tn] = ((const bf16x8*)smem)[(4096 + (wn * 64 + tn * 16 + fr) * 32 + quad * 8) >> 3];
#pragma unroll
    for (int tm = 0; tm < 4; ++tm)
#pragma unroll
      for (int tn = 0; tn < 4; ++tn)
        acc[tm * 4 + tn] = __builtin_amdgcn_mfma_f32_16x16x32_bf16(
            af[tm], bfr[tn], acc[tm * 4 + tn], 0, 0, 0);
    __syncthreads();
  }

#pragma unroll
  for (int tm = 0; tm < 4; ++tm) {
#pragma unroll
    for (int tn = 0; tn < 4; ++tn) {
      int n = n0 + wn * 64 + tn * 16 + fr;        // batch (coalesced)
#pragma unroll
      for (int r = 0; r < 4; ++r) {
        int m = m0 + wm * 64 + tm * 16 + quad * 4 + r;  // dg column index
        float bias = (m < NCOL) ? bdg[m] : 0.f;
        C[(size_t)m * BATCH + n] = acc[tm * 4 + tn][r] + bias;
      }
    }
  }
}

// ---- layer 0: z0T[c][b] = tanh(dgT block · W0 + b0); fused BN stats ----
// lanes along b, wave-uniform t. grid (125, 64), block 256 (4 terms/block).
__global__ void layer0_zT(const float* __restrict__ dgT, const float* __restrict__ W0,
                          const float* __restrict__ b0, float* __restrict__ z0T,
                          float* __restrict__ st) {
  int lane = threadIdx.x & 63, tg = threadIdx.x >> 6;
  int t = blockIdx.x * 4 + tg;
  int b = blockIdx.y * 64 + lane;
  const float* d = dgT + (size_t)(t * GPT) * BATCH + b;
  float x[GPT];
#pragma unroll
  for (int g = 0; g < GPT; ++g) x[g] = d[(size_t)g * BATCH];
#pragma unroll
  for (int h = 0; h < HID; ++h) {
    int c = t * HID + h;
    const float* w = W0 + c * GPT;
    float s = b0[c];
#pragma unroll
    for (int g = 0; g < GPT; ++g) s += x[g] * w[g];
    float z = tanhf(s);
    z0T[(size_t)c * BATCH + b] = z;
    float s1 = z, s2 = z * z;
#pragma unroll
    for (int off = 32; off > 0; off >>= 1) {
      s1 += __shfl_down(s1, off);
      s2 += __shfl_down(s2, off);
    }
    if (lane == 0) {
      atomicAdd(&st[2 * c], s1);
      atomicAdd(&st[2 * c + 1], s2);
    }
  }
}

// ---- BN finalize ----
__global__ void bnfin(const float* __restrict__ st, const float* __restrict__ gam,
                      const float* __restrict__ bet, float* __restrict__ ss, int ncols) {
  int c = blockIdx.x * 256 + threadIdx.x;
  if (c >= ncols) return;
  float m = st[2 * c] * (1.f / BATCH);
  float v = st[2 * c + 1] * (1.f / BATCH) - m * m;
  float sc = gam[c] * rsqrtf(v + BNEPS);
  ss[2 * c] = sc;
  ss[2 * c + 1] = bet[c] - m * sc;
}

// ---- normalize zT + transpose-emit into out[b][outoff + c] ----
__global__ void norm_emit(const float* __restrict__ zT, const float* __restrict__ ss,
                          float* __restrict__ out, int ncols, int outoff) {
  __shared__ float tile[64][65];
  int lane = threadIdx.x & 63, w = threadIdx.x >> 6;
  int c0 = blockIdx.x * 64, b0 = blockIdx.y * 64;
#pragma unroll
  for (int i = 0; i < 16; ++i) {
    int cc = w * 16 + i, c = c0 + cc;
    float n = 0.f;
    if (c < ncols)
      n = zT[(size_t)c * BATCH + b0 + lane] * ss[2 * c] + ss[2 * c + 1];
    tile[cc][lane] = n;
  }
  __syncthreads();
  int c = c0 + lane;
  if (c < ncols) {
#pragma unroll
    for (int i = 0; i < 16; ++i) {
      int rr = w * 16 + i;
      out[(size_t)(b0 + rr) * OUTW + outoff + c] = tile[lane][rr];
    }
  }
}

// ---- aux head: out[b][auxoff+t] = tanh(sum_h n*aw)+... (recompute n from zT) ----
__global__ void aux_head(const float* __restrict__ zT, const float* __restrict__ ss,
                         const float* __restrict__ aw, const float* __restrict__ ab,
                         const float* __restrict__ av, const float* __restrict__ ac,
                         float* __restrict__ out, int nterm, int auxoff) {
  int lane = threadIdx.x & 63, tg = threadIdx.x >> 6;
  int t = blockIdx.x * 4 + tg;
  if (t >= nterm) return;
  int b = blockIdx.y * 64 + lane;
  float s = ab[t];
#pragma unroll
  for (int h = 0; h < HID; ++h) {
    int c = t * HID + h;
    float n = zT[(size_t)c * BATCH + b] * ss[2 * c] + ss[2 * c + 1];
    s += n * aw[c];
  }
  out[(size_t)b * OUTW + auxoff + t] = tanhf(s) * av[t] + ac[t];
}

// ---- layer 1: z1T from normalized z0T children + dgT mid; fused stats ----
__global__ void layer1_zT(const float* __restrict__ dgT, const float* __restrict__ z0T,
                          const float* __restrict__ ss0, const float* __restrict__ W1,
                          const float* __restrict__ b1, float* __restrict__ z1T,
                          float* __restrict__ st) {
  int lane = threadIdx.x & 63, tg = threadIdx.x >> 6;
  int t = blockIdx.x * 4 + tg;
  if (t >= T1N) return;
  int b = blockIdx.y * 64 + lane;
  float x[90];
#pragma unroll
  for (int j = 0; j < 60; ++j) {
    int c = t * 60 + j;
    x[j] = z0T[(size_t)c * BATCH + b] * ss0[2 * c] + ss0[2 * c + 1];
  }
#pragma unroll
  for (int g = 0; g < GPT; ++g)
    x[60 + g] = dgT[(size_t)((T0N + t) * GPT + g) * BATCH + b];
#pragma unroll
  for (int h = 0; h < HID; ++h) {
    int c = t * HID + h;
    const float* w = W1 + c * 90;
    float s = b1[c];
#pragma unroll
    for (int i = 0; i < 90; ++i) s += x[i] * w[i];
    float z = tanhf(s);
    z1T[(size_t)c * BATCH + b] = z;
    float s1 = z, s2 = z * z;
#pragma unroll
    for (int off = 32; off > 0; off >>= 1) {
      s1 += __shfl_down(s1, off);
      s2 += __shfl_down(s2, off);
    }
    if (lane == 0) {
      atomicAdd(&st[2 * c], s1);
      atomicAdd(&st[2 * c + 1], s2);
    }
  }
}

// ---- root: z2T from normalized z1T + dgT root; fused stats ----
__global__ void root_zT(const float* __restrict__ dgT, const float* __restrict__ z1T,
                        const float* __restrict__ ss1, const float* __restrict__ W2,
                        const float* __restrict__ b2, float* __restrict__ z2T,
                        float* __restrict__ st) {
  int b = blockIdx.x * 256 + threadIdx.x;
  int lane = threadIdx.x & 63;
  float s[HID];
#pragma unroll
  for (int h = 0; h < HID; ++h) s[h] = b2[h];
  for (int c = 0; c < 300; ++c) {
    float n = z1T[(size_t)c * BATCH + b] * ss1[2 * c] + ss1[2 * c + 1];
#pragma unroll
    for (int h = 0; h < HID; ++h) s[h] += n * W2[h * 330 + c];
  }
#pragma unroll
  for (int g = 0; g < GPT; ++g) {
    float d = dgT[(size_t)(550 * GPT + g) * BATCH + b];
#pragma unroll
    for (int h = 0; h < HID; ++h) s[h] += d * W2[h * 330 + 300 + g];
  }
#pragma unroll
  for (int h = 0; h < HID; ++h) {
    float z = tanhf(s[h]);
    z2T[(size_t)h * BATCH + b] = z;
    float s1 = z, s2 = z * z;
#pragma unroll
    for (int off = 32; off > 0; off >>= 1) {
      s1 += __shfl_down(s1, off);
      s2 += __shfl_down(s2, off);
    }
    if (lane == 0) {
      atomicAdd(&st[2 * h], s1);
      atomicAdd(&st[2 * h + 1], s2);
    }
  }
}

// ---- root emit: n2 into out + aux2 ----
__global__ void root_emit(const float* __restrict__ z2T, const float* __restrict__ ss2,
                          const float* __restrict__ aw2, const float* __restrict__ ab2,
                          const float* __restrict__ av2, const float* __restrict__ ac2,
                          float* __restrict__ out) {
  int b = blockIdx.x * 256 + threadIdx.x;
  float s = ab2[0];
#pragma unroll
  for (int h = 0; h < HID; ++h) {
    float n = z2T[(size_t)h * BATCH + b] * ss2[2 * h] + ss2[2 * h + 1];
    out[(size_t)b * OUTW + 3851 + h] = n;
    s += n * aw2[h];
  }
  out[(size_t)b * OUTW + 550] = tanhf(s) * av2[0] + ac2[0];
}

extern "C" void kernel_launch(void* const* d_in, const int* in_sizes, int n_in,
                              void* d_out, int out_size, void* d_ws, size_t ws_size,
                              hipStream_t stream) {
  (void)in_sizes; (void)n_in; (void)out_size; (void)ws_size;
  const float* cell = (const float*)d_in[0];
  const float* Wdg  = (const float*)d_in[1];
  const float* bdg  = (const float*)d_in[2];
  const float* W0   = (const float*)d_in[3];
  const float* b0   = (const float*)d_in[4];
  const float* gam0 = (const float*)d_in[5];
  const float* bet0 = (const float*)d_in[6];
  const float* aw0  = (const float*)d_in[7];
  const float* ab0  = (const float*)d_in[8];
  const float* av0  = (const float*)d_in[9];
  const float* ac0  = (const float*)d_in[10];
  const float* W1   = (const float*)d_in[11];
  const float* b1   = (const float*)d_in[12];
  const float* gam1 = (const float*)d_in[13];
  const float* bet1 = (const float*)d_in[14];
  const float* aw1  = (const float*)d_in[15];
  const float* ab1  = (const float*)d_in[16];
  const float* av1  = (const float*)d_in[17];
  const float* ac1  = (const float*)d_in[18];
  const float* W2   = (const float*)d_in[19];
  const float* b2   = (const float*)d_in[20];
  const float* gam2 = (const float*)d_in[21];
  const float* bet2 = (const float*)d_in[22];
  const float* aw2  = (const float*)d_in[23];
  const float* ab2  = (const float*)d_in[24];
  const float* av2  = (const float*)d_in[25];
  const float* ac2  = (const float*)d_in[26];
  float* out = (float*)d_out;

  char* ws = (char*)d_ws;
  unsigned short* cellb = (unsigned short*)(ws);             // 24,641,536 B
  unsigned short* wdgb  = (unsigned short*)(ws + 24641536);  // 100,106,240 B
  float*          dgT   = (float*)(ws + 124747776);          // 272,629,760 B
  // after GEMM, the cast region is dead -> reuse for zT buffers + stats
  float*          z0T   = (float*)(ws);                      // 49,152,000 B
  float*          z1T   = (float*)(ws + 49152000);           // 4,915,200 B
  float*          z2T   = (float*)(ws + 54067200);           // 98,304 B
  float*          st    = (float*)(ws + 54165504);           // 26,448 B
  float*          ssb   = (float*)(ws + 54192000);           // 26,448 B
  float* st0 = st,  *st1 = st + 2 * 3000,  *st2 = st + 2 * 3300;
  float* ss0 = ssb, *ss1 = ssb + 2 * 3000, *ss2 = ssb + 2 * 3300;

  cast_cell<<<6016, 256, 0, stream>>>(cell, (ushort8*)cellb);
  cast_wdg<<<24440, 256, 0, stream>>>(Wdg, (ushort8*)wdgb);
  gemm_dgT<<<dim3(32, 130), 256, 0, stream>>>(wdgb, cellb, bdg, dgT);
  hipMemsetAsync(st, 0, 3306 * 2 * sizeof(float), stream);  // after casts read ws? no: st region disjoint from cast region use — but z0T overlaps cellb, fine (ordered)

  layer0_zT<<<dim3(125, 64), 256, 0, stream>>>(dgT, W0, b0, z0T, st0);
  bnfin<<<12, 256, 0, stream>>>(st0, gam0, bet0, ss0, 3000);
  norm_emit<<<dim3(47, 64), 256, 0, stream>>>(z0T, ss0, out, 3000, 551);
  aux_head<<<dim3(125, 64), 256, 0, stream>>>(z0T, ss0, aw0, ab0, av0, ac0, out, 500, 0);

  layer1_zT<<<dim3(13, 64), 256, 0, stream>>>(dgT, z0T, ss0, W1, b1, z1T, st1);
  bnfin<<<2, 256, 0, stream>>>(st1, gam1, bet1, ss1, 300);
  norm_emit<<<dim3(5, 64), 256, 0, stream>>>(z1T, ss1, out, 300, 3551);
  aux_head<<<dim3(13, 64), 256, 0, stream>>>(z1T, ss1, aw1, ab1, av1, ac1, out, 50, 500);

  root_zT<<<16, 256, 0, stream>>>(dgT, z1T, ss1, W2, b2, z2T, st2);
  bnfin<<<1, 256, 0, stream>>>(st2, gam2, bet2, ss2, 6);
  root_emit<<<16, 256, 0, stream>>>(z2T, ss2, aw2, ab2, av2, ac2, out);
}

// Round 3
// 692.049 us; speedup vs baseline: 2.0472x; 1.7196x over previous
//
#include <hip/hip_runtime.h>
#include <hip/hip_bf16.h>

#define BATCH 4096
#define NGENE 3000
#define HID   6
#define GPT   30
#define T0N   500
#define T1N   50
#define KP    3008    // K padded
#define MROWS 4608    // 3000 (V0 rows) + 1530 (dg mid/root) + 78 pad
#define OUTW  3857
#define BNEPS 1e-5f

typedef __attribute__((ext_vector_type(8))) __bf16 bf16x8;
typedef __attribute__((ext_vector_type(4))) float f32x4;
typedef __attribute__((ext_vector_type(8))) unsigned short ushort8;

__device__ __forceinline__ unsigned short f2bf(float f) {
  unsigned int u = __builtin_bit_cast(unsigned int, f);
  u = (u + 0x7fffu + ((u >> 16) & 1u)) >> 16;
  return (unsigned short)u;
}

__device__ __forceinline__ void gload_lds16(const void* g, void* l) {
  __builtin_amdgcn_global_load_lds(
      (const __attribute__((address_space(1))) unsigned int*)g,
      (__attribute__((address_space(3))) unsigned int*)l, 16, 0, 0);
}

// ---- cast cell fp32 -> bf16, [4096][KP], zero pad ----
__global__ void cast_cell(const float* __restrict__ x, ushort8* __restrict__ y) {
  int idx = blockIdx.x * 256 + threadIdx.x;     // < 4096*376
  int r = idx / 376, c8 = idx - r * 376;
  int c = c8 * 8;
  ushort8 o = (ushort8)0;
  if (c < NGENE) {
    const float4* p = (const float4*)(x + (size_t)r * NGENE + c);
    float4 a = p[0], b = p[1];
    o[0] = f2bf(a.x); o[1] = f2bf(a.y); o[2] = f2bf(a.z); o[3] = f2bf(a.w);
    o[4] = f2bf(b.x); o[5] = f2bf(b.y); o[6] = f2bf(b.z); o[7] = f2bf(b.w);
  }
  y[idx] = o;
}

// ---- V0[t*6+h][n] = sum_g W0[t,h,g]*Wdg[t,g,n], written bf16 into abuf ----
__global__ void v0_build(const float* __restrict__ Wdg, const float* __restrict__ W0,
                         unsigned short* __restrict__ abuf) {
  int n = blockIdx.x * 256 + threadIdx.x;   // gridDim.x=12 -> 3072
  int t = blockIdx.y;
  if (n >= KP) return;
  bool valid = n < NGENE;
  float x[GPT];
#pragma unroll
  for (int g = 0; g < GPT; ++g)
    x[g] = valid ? Wdg[((size_t)(t * GPT + g)) * NGENE + n] : 0.f;
#pragma unroll
  for (int h = 0; h < HID; ++h) {
    const float* w = W0 + (t * HID + h) * GPT;  // wave-uniform
    float s = 0.f;
#pragma unroll
    for (int g = 0; g < GPT; ++g) s += x[g] * w[g];
    abuf[((size_t)(t * HID + h)) * KP + n] = valid ? f2bf(s) : (unsigned short)0;
  }
}

// ---- cast Wdg rows 15000..16529 -> abuf rows 3000..4529 ----
__global__ void cast_wdg_mid(const float* __restrict__ w, ushort8* __restrict__ y) {
  int idx = blockIdx.x * 256 + threadIdx.x;   // < 1530*376
  if (idx >= 1530 * 376) return;
  int r = idx / 376, c8 = idx - r * 376;
  int c = c8 * 8;
  ushort8 o = (ushort8)0;
  if (c < NGENE) {
    const float4* p = (const float4*)(w + (size_t)(15000 + r) * NGENE + c);
    float4 a = p[0], b = p[1];
    o[0] = f2bf(a.x); o[1] = f2bf(a.y); o[2] = f2bf(a.z); o[3] = f2bf(a.w);
    o[4] = f2bf(b.x); o[5] = f2bf(b.y); o[6] = f2bf(b.z); o[7] = f2bf(b.w);
  }
  y[(size_t)(3000 + r) * 376 + c8] = o;
}

// ---- zero abuf rows 4530..4607 ----
__global__ void zero_tail(ushort8* __restrict__ y) {
  int idx = blockIdx.x * 256 + threadIdx.x;   // < 78*376
  if (idx < 78 * 376) y[(size_t)4530 * 376 + idx] = (ushort8)0;
}

// ---- bias: rows<3000 -> b0 + W0·bdg ; 3000..4529 -> bdg[15000+..] ; else 0 ----
__global__ void build_bias(const float* __restrict__ bdg, const float* __restrict__ W0,
                           const float* __restrict__ b0, float* __restrict__ bias) {
  int idx = blockIdx.x * 256 + threadIdx.x;
  if (idx >= MROWS) return;
  float v = 0.f;
  if (idx < 3000) {
    int t = idx / HID;
    float s = b0[idx];
#pragma unroll
    for (int g = 0; g < GPT; ++g) s += W0[idx * GPT + g] * bdg[t * GPT + g];
    v = s;
  } else if (idx < 4530) {
    v = bdg[15000 + idx - 3000];
  }
  bias[idx] = v;
}

// ---- GEMM: C[m][b] = A[m,:]·cell[b,:] + bias[m]; tanh for m<3000 ----
__global__ __launch_bounds__(256) void gemm_fused(
    const unsigned short* __restrict__ A,    // [MROWS][KP] bf16
    const unsigned short* __restrict__ Bt,   // [BATCH][KP] bf16
    const float* __restrict__ bias,
    float* __restrict__ C) {                 // [MROWS][BATCH] fp32
  __shared__ unsigned short smem[8192];
  const int tid  = threadIdx.x;
  const int wave = tid >> 6, lane = tid & 63;
  const int wm = wave >> 1, wn = wave & 1;
  const int quad = lane >> 4, fr = lane & 15;
  const int m0 = blockIdx.y * 128, n0 = blockIdx.x * 128;
  const int lrow = lane >> 2;
  const int lcol = (lane & 3) * 8;

  f32x4 acc[16] = {};

  for (int kt = 0; kt < KP / 32; ++kt) {
    const int k0 = kt * 32;
#pragma unroll
    for (int q = 0; q < 4; ++q) {
      int chunk = q * 4 + wave;
      const unsigned short* gsrc;
      if (chunk < 8) {
        int row = m0 + chunk * 16 + lrow;
        gsrc = A + (size_t)row * KP + k0 + lcol;
      } else {
        int row = n0 + (chunk - 8) * 16 + lrow;
        gsrc = Bt + (size_t)row * KP + k0 + lcol;
      }
      gload_lds16(gsrc, &smem[chunk * 512]);
    }
    asm volatile("s_waitcnt vmcnt(0)" ::: "memory");
    __syncthreads();

    bf16x8 af[4], bfr[4];
#pragma unroll
    for (int tm = 0; tm < 4; ++tm)
      af[tm] = ((const bf16x8*)smem)[((wm * 64 + tm * 16 + fr) * 32 + quad * 8) >> 3];
#pragma unroll
    for (int tn = 0; tn < 4; ++tn)
      bfr[tn] = ((const bf16x8*)smem)[(4096 + (wn * 64 + tn * 16 + fr) * 32 + quad * 8) >> 3];
#pragma unroll
    for (int tm = 0; tm < 4; ++tm)
#pragma unroll
      for (int tn = 0; tn < 4; ++tn)
        acc[tm * 4 + tn] = __builtin_amdgcn_mfma_f32_16x16x32_bf16(
            af[tm], bfr[tn], acc[tm * 4 + tn], 0, 0, 0);
    __syncthreads();
  }

#pragma unroll
  for (int tm = 0; tm < 4; ++tm) {
#pragma unroll
    for (int tn = 0; tn < 4; ++tn) {
      int n = n0 + wn * 64 + tn * 16 + fr;   // batch, coalesced
#pragma unroll
      for (int r = 0; r < 4; ++r) {
        int m = m0 + wm * 64 + tm * 16 + quad * 4 + r;
        float v = acc[tm * 4 + tn][r] + bias[m];
        if (m < 3000) v = tanhf(v);          // layer-0 activation fused
        C[(size_t)m * BATCH + n] = v;
      }
    }
  }
}

// ---- column stats over batch, one block per column (z0T layout [c][b]) ----
__global__ void colstatsT(const float* __restrict__ zT, float* __restrict__ st, int ncols) {
  int c = blockIdx.x;
  if (c >= ncols) return;
  const float* p = zT + (size_t)c * BATCH;
  float s = 0.f, q = 0.f;
  for (int i = threadIdx.x; i < BATCH; i += 256) {
    float v = p[i];
    s += v; q += v * v;
  }
#pragma unroll
  for (int off = 32; off > 0; off >>= 1) {
    s += __shfl_down(s, off);
    q += __shfl_down(q, off);
  }
  __shared__ float ls[8];
  int lane = threadIdx.x & 63, w = threadIdx.x >> 6;
  if (lane == 0) { ls[2 * w] = s; ls[2 * w + 1] = q; }
  __syncthreads();
  if (threadIdx.x == 0) {
    st[2 * c]     = ls[0] + ls[2] + ls[4] + ls[6];
    st[2 * c + 1] = ls[1] + ls[3] + ls[5] + ls[7];
  }
}

// ---- BN finalize ----
__global__ void bnfin(const float* __restrict__ st, const float* __restrict__ gam,
                      const float* __restrict__ bet, float* __restrict__ ss, int ncols) {
  int c = blockIdx.x * 256 + threadIdx.x;
  if (c >= ncols) return;
  float m = st[2 * c] * (1.f / BATCH);
  float v = st[2 * c + 1] * (1.f / BATCH) - m * m;
  float sc = gam[c] * rsqrtf(v + BNEPS);
  ss[2 * c] = sc;
  ss[2 * c + 1] = bet[c] - m * sc;
}

// ---- normalize zT + transpose-emit into out[b][outoff + c] ----
__global__ void norm_emit(const float* __restrict__ zT, const float* __restrict__ ss,
                          float* __restrict__ out, int ncols, int outoff) {
  __shared__ float tile[64][65];
  int lane = threadIdx.x & 63, w = threadIdx.x >> 6;
  int c0 = blockIdx.x * 64, b0 = blockIdx.y * 64;
#pragma unroll
  for (int i = 0; i < 16; ++i) {
    int cc = w * 16 + i, c = c0 + cc;
    float n = 0.f;
    if (c < ncols)
      n = zT[(size_t)c * BATCH + b0 + lane] * ss[2 * c] + ss[2 * c + 1];
    tile[cc][lane] = n;
  }
  __syncthreads();
  int c = c0 + lane;
  if (c < ncols) {
#pragma unroll
    for (int i = 0; i < 16; ++i) {
      int rr = w * 16 + i;
      out[(size_t)(b0 + rr) * OUTW + outoff + c] = tile[lane][rr];
    }
  }
}

// ---- aux head ----
__global__ void aux_head(const float* __restrict__ zT, const float* __restrict__ ss,
                         const float* __restrict__ aw, const float* __restrict__ ab,
                         const float* __restrict__ av, const float* __restrict__ ac,
                         float* __restrict__ out, int nterm, int auxoff) {
  int lane = threadIdx.x & 63, tg = threadIdx.x >> 6;
  int t = blockIdx.x * 4 + tg;
  if (t >= nterm) return;
  int b = blockIdx.y * 64 + lane;
  float s = ab[t];
#pragma unroll
  for (int h = 0; h < HID; ++h) {
    int c = t * HID + h;
    float n = zT[(size_t)c * BATCH + b] * ss[2 * c] + ss[2 * c + 1];
    s += n * aw[c];
  }
  out[(size_t)b * OUTW + auxoff + t] = tanhf(s) * av[t] + ac[t];
}

// ---- layer 1: z1T from normalized z0T children + raw dg mid; fused stats ----
__global__ void layer1_zT(const float* __restrict__ C, const float* __restrict__ ss0,
                          const float* __restrict__ W1, const float* __restrict__ b1,
                          float* __restrict__ z1T, float* __restrict__ st) {
  int lane = threadIdx.x & 63, tg = threadIdx.x >> 6;
  int t = blockIdx.x * 4 + tg;
  if (t >= T1N) return;
  int b = blockIdx.y * 64 + lane;
  const float* z0T = C;
  const float* dgm = C + (size_t)3000 * BATCH;
  float x[90];
#pragma unroll
  for (int j = 0; j < 60; ++j) {
    int c = t * 60 + j;
    x[j] = z0T[(size_t)c * BATCH + b] * ss0[2 * c] + ss0[2 * c + 1];
  }
#pragma unroll
  for (int g = 0; g < GPT; ++g)
    x[60 + g] = dgm[(size_t)(t * GPT + g) * BATCH + b];
#pragma unroll
  for (int h = 0; h < HID; ++h) {
    int c = t * HID + h;
    const float* w = W1 + c * 90;
    float s = b1[c];
#pragma unroll
    for (int i = 0; i < 90; ++i) s += x[i] * w[i];
    float z = tanhf(s);
    z1T[(size_t)c * BATCH + b] = z;
    float s1 = z, s2 = z * z;
#pragma unroll
    for (int off = 32; off > 0; off >>= 1) {
      s1 += __shfl_down(s1, off);
      s2 += __shfl_down(s2, off);
    }
    if (lane == 0) {
      atomicAdd(&st[2 * c], s1);
      atomicAdd(&st[2 * c + 1], s2);
    }
  }
}

// ---- root ----
__global__ void root_zT(const float* __restrict__ C, const float* __restrict__ z1T,
                        const float* __restrict__ ss1, const float* __restrict__ W2,
                        const float* __restrict__ b2, float* __restrict__ z2T,
                        float* __restrict__ st) {
  int b = blockIdx.x * 256 + threadIdx.x;
  int lane = threadIdx.x & 63;
  const float* dgr = C + (size_t)4500 * BATCH;
  float s[HID];
#pragma unroll
  for (int h = 0; h < HID; ++h) s[h] = b2[h];
  for (int c = 0; c < 300; ++c) {
    float n = z1T[(size_t)c * BATCH + b] * ss1[2 * c] + ss1[2 * c + 1];
#pragma unroll
    for (int h = 0; h < HID; ++h) s[h] += n * W2[h * 330 + c];
  }
#pragma unroll
  for (int g = 0; g < GPT; ++g) {
    float d = dgr[(size_t)g * BATCH + b];
#pragma unroll
    for (int h = 0; h < HID; ++h) s[h] += d * W2[h * 330 + 300 + g];
  }
#pragma unroll
  for (int h = 0; h < HID; ++h) {
    float z = tanhf(s[h]);
    z2T[(size_t)h * BATCH + b] = z;
    float s1 = z, s2 = z * z;
#pragma unroll
    for (int off = 32; off > 0; off >>= 1) {
      s1 += __shfl_down(s1, off);
      s2 += __shfl_down(s2, off);
    }
    if (lane == 0) {
      atomicAdd(&st[2 * h], s1);
      atomicAdd(&st[2 * h + 1], s2);
    }
  }
}

__global__ void root_emit(const float* __restrict__ z2T, const float* __restrict__ ss2,
                          const float* __restrict__ aw2, const float* __restrict__ ab2,
                          const float* __restrict__ av2, const float* __restrict__ ac2,
                          float* __restrict__ out) {
  int b = blockIdx.x * 256 + threadIdx.x;
  float s = ab2[0];
#pragma unroll
  for (int h = 0; h < HID; ++h) {
    float n = z2T[(size_t)h * BATCH + b] * ss2[2 * h] + ss2[2 * h + 1];
    out[(size_t)b * OUTW + 3851 + h] = n;
    s += n * aw2[h];
  }
  out[(size_t)b * OUTW + 550] = tanhf(s) * av2[0] + ac2[0];
}

extern "C" void kernel_launch(void* const* d_in, const int* in_sizes, int n_in,
                              void* d_out, int out_size, void* d_ws, size_t ws_size,
                              hipStream_t stream) {
  (void)in_sizes; (void)n_in; (void)out_size; (void)ws_size;
  const float* cell = (const float*)d_in[0];
  const float* Wdg  = (const float*)d_in[1];
  const float* bdg  = (const float*)d_in[2];
  const float* W0   = (const float*)d_in[3];
  const float* b0   = (const float*)d_in[4];
  const float* gam0 = (const float*)d_in[5];
  const float* bet0 = (const float*)d_in[6];
  const float* aw0  = (const float*)d_in[7];
  const float* ab0  = (const float*)d_in[8];
  const float* av0  = (const float*)d_in[9];
  const float* ac0  = (const float*)d_in[10];
  const float* W1   = (const float*)d_in[11];
  const float* b1   = (const float*)d_in[12];
  const float* gam1 = (const float*)d_in[13];
  const float* bet1 = (const float*)d_in[14];
  const float* aw1  = (const float*)d_in[15];
  const float* ab1  = (const float*)d_in[16];
  const float* av1  = (const float*)d_in[17];
  const float* ac1  = (const float*)d_in[18];
  const float* W2   = (const float*)d_in[19];
  const float* b2   = (const float*)d_in[20];
  const float* gam2 = (const float*)d_in[21];
  const float* bet2 = (const float*)d_in[22];
  const float* aw2  = (const float*)d_in[23];
  const float* ab2  = (const float*)d_in[24];
  const float* av2  = (const float*)d_in[25];
  const float* ac2  = (const float*)d_in[26];
  float* out = (float*)d_out;

  char* ws = (char*)d_ws;
  unsigned short* cellb = (unsigned short*)(ws);               // 24,641,536
  unsigned short* abuf  = (unsigned short*)(ws + 24641536);    // 27,721,728
  float*          C     = (float*)(ws + 52363264);             // 75,497,472
  float*          z1T   = (float*)(ws + 127860736);            // 4,915,200
  float*          z2T   = (float*)(ws + 132775936);            // 98,304
  float*          st    = (float*)(ws + 132874240);            // 26,448 (pad 32768)
  float*          ssb   = (float*)(ws + 132907008);            // 26,448 (pad 32768)
  float*          bias  = (float*)(ws + 132939776);            // 18,432
  float* st0 = st,  *st1 = st + 2 * 3000,  *st2 = st + 2 * 3300;
  float* ss0 = ssb, *ss1 = ssb + 2 * 3000, *ss2 = ssb + 2 * 3300;

  hipMemsetAsync(st, 0, 32768, stream);   // layer1/root atomic accumulators
  cast_cell<<<6016, 256, 0, stream>>>(cell, (ushort8*)cellb);
  v0_build<<<dim3(12, T0N), 256, 0, stream>>>(Wdg, W0, abuf);
  cast_wdg_mid<<<2248, 256, 0, stream>>>(Wdg, (ushort8*)abuf);
  zero_tail<<<115, 256, 0, stream>>>((ushort8*)abuf);
  build_bias<<<18, 256, 0, stream>>>(bdg, W0, b0, bias);

  gemm_fused<<<dim3(32, 36), 256, 0, stream>>>(abuf, cellb, bias, C);

  colstatsT<<<3000, 256, 0, stream>>>(C, st0, 3000);
  bnfin<<<12, 256, 0, stream>>>(st0, gam0, bet0, ss0, 3000);
  norm_emit<<<dim3(47, 64), 256, 0, stream>>>(C, ss0, out, 3000, 551);
  aux_head<<<dim3(125, 64), 256, 0, stream>>>(C, ss0, aw0, ab0, av0, ac0, out, 500, 0);

  layer1_zT<<<dim3(13, 64), 256, 0, stream>>>(C, ss0, W1, b1, z1T, st1);
  bnfin<<<2, 256, 0, stream>>>(st1, gam1, bet1, ss1, 300);
  norm_emit<<<dim3(5, 64), 256, 0, stream>>>(z1T, ss1, out, 300, 3551);
  aux_head<<<dim3(13, 64), 256, 0, stream>>>(z1T, ss1, aw1, ab1, av1, ac1, out, 50, 500);

  root_zT<<<16, 256, 0, stream>>>(C, z1T, ss1, W2, b2, z2T, st2);
  bnfin<<<1, 256, 0, stream>>>(st2, gam2, bet2, ss2, 6);
  root_emit<<<16, 256, 0, stream>>>(z2T, ss2, aw2, ab2, av2, ac2, out);
}